// Round 3
// baseline (58.573 us; speedup 1.0000x reference)
//
#include <hip/hip_runtime.h>

// 3x3 majority filter, replicate pad, 8 bins, ties -> smallest label, 8 iters.
// Single fused kernel: each block owns a 48x48 output tile, staged as a 64x64
// (halo-8) u8 tile in LDS, iterated 8x entirely in LDS. Full-tile uniform
// compute with window clamping at tile bounds; tile-edge corruption moves
// inward 1 px/iter and stays inside the 8-px halo. For image-edge tiles the
// clamp bound is placed at the true image edge (tile coord 8 / 55), which
// reproduces replicate-pad semantics exactly.
//
// Histogram: u64, one byte per bin, counts scaled x8, tie tag (7-bin) baked
// into the sliding window sum once per row. Argmax = byte max -> (m&7)^7.

static constexpr int IMG  = 768;
static constexpr int TILE = 48;
static constexpr int IT   = 64;          // input tile (TILE + 2*8)
static constexpr int NB   = IMG / TILE;  // 16
static constexpr unsigned long long TAG = 0x0001020304050607ull;

__device__ __forceinline__ unsigned long long enc8(unsigned int l) {
    return 8ull << (l << 3);
}
__device__ __forceinline__ unsigned int umax2(unsigned int a, unsigned int b) {
    return a > b ? a : b;
}
__device__ __forceinline__ unsigned int umax3(unsigned int a, unsigned int b, unsigned int c) {
    return umax2(umax2(a, b), c);   // -> v_max3_u32
}
__device__ __forceinline__ unsigned int argdec(unsigned long long h) {
    unsigned int lo = (unsigned int)h;
    unsigned int hi = (unsigned int)(h >> 32);
    unsigned int m1 = umax3(lo & 255u, (lo >> 8) & 255u, (lo >> 16) & 255u);
    unsigned int m2 = umax3(lo >> 24, hi & 255u, (hi >> 8) & 255u);
    unsigned int m3 = umax3((hi >> 16) & 255u, hi >> 24, m1);
    unsigned int m  = umax2(m2, m3);
    return (m & 7u) ^ 7u;
}

__global__ __launch_bounds__(256, 6) void fused_majority(
    const float* __restrict__ in, float* __restrict__ out) {

    __shared__ __align__(16) unsigned char buf[2][IT * IT];

    const int bx = blockIdx.x, by = blockIdx.y, bz = blockIdx.z;
    const int tid = threadIdx.x;

    const float* img = in + (size_t)bz * IMG * IMG;
    float* oimg      = out + (size_t)bz * IMG * IMG;

    // ---- stage: clamped 64x64 window of f32 labels -> u8 tile in buf[0]
    {
        const int row = tid >> 2;
        const int seg = (tid & 3) << 4;
        int gy = by * TILE - 8 + row;
        gy = gy < 0 ? 0 : (gy > IMG - 1 ? IMG - 1 : gy);
        const float* rp = img + (size_t)gy * IMG;
        const int gx0 = bx * TILE - 8 + seg;

        float f[16];
        if (gx0 >= 0 && gx0 + 16 <= IMG) {
            *(float4*)(f + 0)  = *(const float4*)(rp + gx0 + 0);
            *(float4*)(f + 4)  = *(const float4*)(rp + gx0 + 4);
            *(float4*)(f + 8)  = *(const float4*)(rp + gx0 + 8);
            *(float4*)(f + 12) = *(const float4*)(rp + gx0 + 12);
        } else {
#pragma unroll
            for (int i = 0; i < 16; ++i) {
                int g = gx0 + i;
                g = g < 0 ? 0 : (g > IMG - 1 ? IMG - 1 : g);
                f[i] = rp[g];
            }
        }
        unsigned long long p0 = 0, p1 = 0;
#pragma unroll
        for (int i = 0; i < 8; ++i) {
            p0 |= (unsigned long long)((unsigned int)(int)f[i] & 7u) << (i << 3);
            p1 |= (unsigned long long)((unsigned int)(int)f[i + 8] & 7u) << (i << 3);
        }
        unsigned long long* w = (unsigned long long*)&buf[0][row * IT + seg];
        w[0] = p0;
        w[1] = p1;
    }
    __syncthreads();

    const int xc = tid & 7;     // 8-px column chunk
    const int yr = tid >> 3;    // 0..31, owns rows 2*yr, 2*yr+1
    const int r0 = yr << 1;
    const int r1 = r0 | 1;

    // Clamp bounds: at true image edges, clamp at the image-edge position in
    // tile coords (replicate-pad); at interior tile edges, clamp at the tile
    // bound (corruption contained in halo).
    const int xlo = (bx == 0)      ? 8      : 0;
    const int xhi = (bx == NB - 1) ? IT - 9 : IT - 1;
    const int ylo = (by == 0)      ? 8      : 0;
    const int yhi = (by == NB - 1) ? IT - 9 : IT - 1;

    int rm = r0 - 1; rm = rm < ylo ? ylo : rm;
    int rq = r1 + 1; rq = rq > yhi ? yhi : rq;

    const int om = xc << 3;
    int bl = om - 1; bl = bl < xlo ? xlo : bl;
    int br = om + 8; br = br > xhi ? xhi : br;

    unsigned long long outpack[2] = {0, 0};

    for (int it = 0; it < 8; ++it) {
        const unsigned char* src = buf[it & 1];
        const unsigned char* prm = src + rm * IT;
        const unsigned char* pr0 = src + r0 * IT;
        const unsigned char* pr1 = src + r1 * IT;
        const unsigned char* prq = src + rq * IT;

        const unsigned long long m0 = *(const unsigned long long*)(prm + om);
        const unsigned long long m1 = *(const unsigned long long*)(pr0 + om);
        const unsigned long long m2 = *(const unsigned long long*)(pr1 + om);
        const unsigned long long m3 = *(const unsigned long long*)(prq + om);
        const unsigned int la = prm[bl], lbv = pr0[bl], lc = pr1[bl], ld = prq[bl];
        const unsigned int qa = prm[br], qbv = pr0[br], qc = pr1[br], qd = prq[br];

        // Column hists for window rows (rm, r0, r1) -> output row r0.
        unsigned long long ch[10];
        ch[0] = enc8(la & 7u) + enc8(lbv & 7u) + enc8(lc & 7u);
#pragma unroll
        for (int j = 0; j < 8; ++j) {
            const unsigned int a = (unsigned int)(m0 >> (j << 3)) & 7u;
            const unsigned int b = (unsigned int)(m1 >> (j << 3)) & 7u;
            const unsigned int c = (unsigned int)(m2 >> (j << 3)) & 7u;
            ch[j + 1] = enc8(a) + enc8(b) + enc8(c);
        }
        ch[9] = enc8(qa & 7u) + enc8(qbv & 7u) + enc8(qc & 7u);

        {
            unsigned long long s = ch[0] + ch[1] + ch[2] + TAG;
            unsigned long long pk = 0;
#pragma unroll
            for (int j = 0; j < 8; ++j) {
                pk |= (unsigned long long)argdec(s) << (j << 3);
                if (j < 7) s = s + ch[j + 3] - ch[j];
            }
            outpack[0] = pk;
        }

        // Vertical slide: window rows (r0, r1, rq) -> output row r1.
        ch[0] = ch[0] + enc8(ld & 7u) - enc8(la & 7u);
#pragma unroll
        for (int j = 0; j < 8; ++j) {
            const unsigned int a = (unsigned int)(m0 >> (j << 3)) & 7u;
            const unsigned int d = (unsigned int)(m3 >> (j << 3)) & 7u;
            ch[j + 1] = ch[j + 1] + enc8(d) - enc8(a);
        }
        ch[9] = ch[9] + enc8(qd & 7u) - enc8(qa & 7u);

        {
            unsigned long long s = ch[0] + ch[1] + ch[2] + TAG;
            unsigned long long pk = 0;
#pragma unroll
            for (int j = 0; j < 8; ++j) {
                pk |= (unsigned long long)argdec(s) << (j << 3);
                if (j < 7) s = s + ch[j + 3] - ch[j];
            }
            outpack[1] = pk;
        }

        if (it < 7) {
            unsigned char* dst = buf[(it + 1) & 1];
            *(unsigned long long*)(dst + r0 * IT + om) = outpack[0];
            *(unsigned long long*)(dst + r1 * IT + om) = outpack[1];
            __syncthreads();
        }
    }

    // ---- final store (f32): valid region = tile [8,56) x [8,56)
    if (xc >= 1 && xc <= 6 && r0 >= 8 && r0 < 8 + TILE) {
        const int gx = bx * TILE + ((xc - 1) << 3);
#pragma unroll
        for (int rr = 0; rr < 2; ++rr) {
            const int r = r0 + rr;
            const int gy = by * TILE + r - 8;
            const unsigned long long pk = outpack[rr];
            float* op = oimg + (size_t)gy * IMG + gx;
            float4 f0, f1;
            f0.x = (float)((unsigned int)(pk >> 0)  & 7u);
            f0.y = (float)((unsigned int)(pk >> 8)  & 7u);
            f0.z = (float)((unsigned int)(pk >> 16) & 7u);
            f0.w = (float)((unsigned int)(pk >> 24) & 7u);
            f1.x = (float)((unsigned int)(pk >> 32) & 7u);
            f1.y = (float)((unsigned int)(pk >> 40) & 7u);
            f1.z = (float)((unsigned int)(pk >> 48) & 7u);
            f1.w = (float)((unsigned int)(pk >> 56) & 7u);
            *(float4*)(op + 0) = f0;
            *(float4*)(op + 4) = f1;
        }
    }
}

extern "C" void kernel_launch(void* const* d_in, const int* in_sizes, int n_in,
                              void* d_out, int out_size, void* d_ws, size_t ws_size,
                              hipStream_t stream) {
    const float* clusters = (const float*)d_in[0];
    (void)in_sizes; (void)n_in; (void)out_size; (void)d_ws; (void)ws_size;

    dim3 grid(NB, NB, 8);   // 16 x 16 tiles x batch 8
    fused_majority<<<grid, 256, 0, stream>>>(clusters, (float*)d_out);
}

// Round 4
// 45.075 us; speedup vs baseline: 1.2995x; 1.2995x over previous
//
#include <hip/hip_runtime.h>

// 3x3 majority filter, replicate pad, 8 bins, ties -> smallest, 8 iterations.
// Bit-sliced: labels (3 bits) kept as 3 bit-planes; one u32 = 32 columns.
// Per iter: 8 equality masks -> vertical 2-bit bit-sliced counts ->
// horizontal funnel-shift + bit-sliced add (4-bit counts) -> sequential
// bit-sliced argmax over bins (strict >, scan 0..7 => first max = smallest).
// Thread = one 32-col word-row; block = 128 threads = one 64x64 halo tile.
// LDS holds only per-row equality masks (ping-pong), 48B stride.

static constexpr int IMG = 768;
static constexpr int OUT = 48;
static constexpr int NB  = 16;   // IMG / OUT

__device__ __forceinline__ unsigned bfi(unsigned m, unsigned a, unsigned b) {
    return (a & m) | (b & ~m);   // -> v_bfi_b32
}
// bit j = cur[j-1], bit 0 = left[31]   (shift window left operand)
__device__ __forceinline__ unsigned funl(unsigned cur, unsigned left) {
    return (cur << 1) | (left >> 31);  // -> v_alignbit_b32
}
// bit j = cur[j+1], bit 31 = right[0]
__device__ __forceinline__ unsigned funr(unsigned cur, unsigned right) {
    return (cur >> 1) | (right << 31);
}

__global__ __launch_bounds__(128) void fused_bitslice(
    const float* __restrict__ in, float* __restrict__ out) {

  // per rowword: 8 bin masks + 4 pad -> 48B stride (bank-conflict floor)
  __shared__ unsigned eqb[2][128 * 12];

  const int bx = blockIdx.x, by = blockIdx.y, bz = blockIdx.z;
  const int tid = threadIdx.x;
  const int w = tid & 1;        // word (32-col half) of the 64-wide tile
  const int r = tid >> 1;       // tile row 0..63

  const float* img = in + (size_t)bz * IMG * IMG;

  // ---- stage: 32 clamped labels -> 3 bit-planes
  unsigned p0 = 0, p1 = 0, p2 = 0;
  {
    int gy = by * OUT + r - 8;
    gy = gy < 0 ? 0 : (gy > IMG - 1 ? IMG - 1 : gy);
    const float* rp = img + (size_t)gy * IMG;
    const int gx0 = bx * OUT + w * 32 - 8;
    float f[32];
    if (gx0 >= 0 && gx0 + 32 <= IMG) {
#pragma unroll
      for (int g = 0; g < 8; ++g)
        *(float4*)(f + 4 * g) = *(const float4*)(rp + gx0 + 4 * g);
    } else {
#pragma unroll
      for (int j = 0; j < 32; ++j) {
        int gx = gx0 + j; gx = gx < 0 ? 0 : (gx > IMG - 1 ? IMG - 1 : gx);
        f[j] = rp[gx];
      }
    }
#pragma unroll
    for (int j = 0; j < 32; ++j) {
      unsigned u = (unsigned)(int)f[j];
      p0 |= (u & 1u) << j;
      p1 |= ((u >> 1) & 1u) << j;
      p2 |= ((u >> 2) & 1u) << j;
    }
  }

  // Row clamps: at true image edge clamp at image-edge tile coord (8 / 55)
  // -> exact replicate semantics; at interior tile edges clamp to tile
  // (corruption stays in the 8-px halo: 1 px/iter * 8 iters).
  const int rlo = (by == 0)      ? 8  : 0;
  const int rhi = (by == NB - 1) ? 55 : 63;
  const int rm = (r - 1 < rlo) ? rlo : r - 1;
  const int rq = (r + 1 > rhi) ? rhi : r + 1;

  const int selfIdx = (r * 2 + w) * 12;
  const int mwIdx = (rm * 2 + w) * 12;
  const int qwIdx = (rq * 2 + w) * 12;
  // horizontal neighbor words (clamped): left word index = 0, right = 1
  const int mlIdx = (rm * 2 + 0) * 12, clIdx = (r * 2 + 0) * 12, qlIdx = (rq * 2 + 0) * 12;
  const int mrIdx = (rm * 2 + 1) * 12, crIdx = (r * 2 + 1) * 12, qrIdx = (rq * 2 + 1) * 12;

  const bool patchL = (bx == 0) && (w == 0);       // replicate at image col 0 (tile col 8)
  const bool patchR = (bx == NB - 1) && (w == 1);  // replicate at image col 767 (tile col 55)

  unsigned eo[8];

  for (int it = 0; it < 8; ++it) {
    unsigned* B = eqb[it & 1];

    // equality masks of own row from planes (15 ops)
    {
      unsigned n0 = ~p0, n1 = ~p1, n2 = ~p2;
      unsigned a00 = n1 & n0, a01 = n1 & p0, a10 = p1 & n0, a11 = p1 & p0;
      eo[0] = n2 & a00; eo[1] = n2 & a01; eo[2] = n2 & a10; eo[3] = n2 & a11;
      eo[4] = p2 & a00; eo[5] = p2 & a01; eo[6] = p2 & a10; eo[7] = p2 & a11;
    }
    *(uint4*)&B[selfIdx]     = make_uint4(eo[0], eo[1], eo[2], eo[3]);
    *(uint4*)&B[selfIdx + 4] = make_uint4(eo[4], eo[5], eo[6], eo[7]);
    __syncthreads();

    unsigned Cl[8], Ch[8], Ll[8], Lh[8], Rl[8], Rh[8];

    // own-word vertical counts (rows rm, r, rq)
    {
      uint4 m0 = *(const uint4*)&B[mwIdx], m1 = *(const uint4*)&B[mwIdx + 4];
      uint4 q0 = *(const uint4*)&B[qwIdx], q1 = *(const uint4*)&B[qwIdx + 4];
      unsigned em[8] = {m0.x, m0.y, m0.z, m0.w, m1.x, m1.y, m1.z, m1.w};
      unsigned eq_[8] = {q0.x, q0.y, q0.z, q0.w, q1.x, q1.y, q1.z, q1.w};
#pragma unroll
      for (int b = 0; b < 8; ++b) {
        unsigned t = em[b] ^ eo[b];
        Cl[b] = t ^ eq_[b];
        Ch[b] = bfi(t, eq_[b], eo[b]);   // majority(em, eo, eq_)
      }
    }
    // left-word vertical counts
    {
      uint4 a0 = *(const uint4*)&B[mlIdx], a1 = *(const uint4*)&B[mlIdx + 4];
      uint4 b0 = *(const uint4*)&B[clIdx], b1 = *(const uint4*)&B[clIdx + 4];
      uint4 c0 = *(const uint4*)&B[qlIdx], c1 = *(const uint4*)&B[qlIdx + 4];
      unsigned la[8] = {a0.x, a0.y, a0.z, a0.w, a1.x, a1.y, a1.z, a1.w};
      unsigned lb[8] = {b0.x, b0.y, b0.z, b0.w, b1.x, b1.y, b1.z, b1.w};
      unsigned lc[8] = {c0.x, c0.y, c0.z, c0.w, c1.x, c1.y, c1.z, c1.w};
#pragma unroll
      for (int b = 0; b < 8; ++b) {
        unsigned t = la[b] ^ lb[b];
        Ll[b] = t ^ lc[b];
        Lh[b] = bfi(t, lc[b], lb[b]);
      }
    }
    // right-word vertical counts
    {
      uint4 a0 = *(const uint4*)&B[mrIdx], a1 = *(const uint4*)&B[mrIdx + 4];
      uint4 b0 = *(const uint4*)&B[crIdx], b1 = *(const uint4*)&B[crIdx + 4];
      uint4 c0 = *(const uint4*)&B[qrIdx], c1 = *(const uint4*)&B[qrIdx + 4];
      unsigned ra[8] = {a0.x, a0.y, a0.z, a0.w, a1.x, a1.y, a1.z, a1.w};
      unsigned rb[8] = {b0.x, b0.y, b0.z, b0.w, b1.x, b1.y, b1.z, b1.w};
      unsigned rc[8] = {c0.x, c0.y, c0.z, c0.w, c1.x, c1.y, c1.z, c1.w};
#pragma unroll
      for (int b = 0; b < 8; ++b) {
        unsigned t = ra[b] ^ rb[b];
        Rl[b] = t ^ rc[b];
        Rh[b] = bfi(t, rc[b], rb[b]);
      }
    }

    // horizontal add + bit-sliced argmax scan
    unsigned w0, w1, w2, w3, i0, i1, i2;
#pragma unroll
    for (int b = 0; b < 8; ++b) {
      unsigned A0 = funl(Cl[b], Ll[b]);
      unsigned A1 = funl(Ch[b], Lh[b]);
      unsigned C0 = funr(Cl[b], Rl[b]);
      unsigned C1 = funr(Ch[b], Rh[b]);
      if (patchL) { A0 = bfi(0x100u, Cl[b], A0); A1 = bfi(0x100u, Ch[b], A1); }
      if (patchR) { C0 = bfi(0x800000u, Cl[b], C0); C1 = bfi(0x800000u, Ch[b], C1); }
      // (A + B): 2-bit + 2-bit -> 3-bit (s0, s1, cs)
      unsigned s0 = A0 ^ Cl[b], cc = A0 & Cl[b];
      unsigned u  = A1 ^ Ch[b];
      unsigned s1 = u ^ cc, cs = bfi(u, cc, Ch[b]);
      // + C: 3-bit + 2-bit -> 4-bit (t0..t3)
      unsigned t0 = s0 ^ C0, k0 = s0 & C0;
      unsigned v  = s1 ^ C1;
      unsigned t1 = v ^ k0, k1 = bfi(v, k0, C1);
      unsigned t2 = cs ^ k1, t3 = cs & k1;

      if (b == 0) {
        w0 = t0; w1 = t1; w2 = t2; w3 = t3; i0 = i1 = i2 = 0;
      } else {
        unsigned g3 = bfi(w3, 0u, t3), x3 = t3 ^ w3;
        unsigned g2 = bfi(w2, 0u, t2), x2 = t2 ^ w2;
        unsigned g1 = bfi(w1, 0u, t1), x1 = t1 ^ w1;
        unsigned g0 = bfi(w0, 0u, t0);
        unsigned h = bfi(x1, 0u, g0);
        h = g1 | h;
        h = bfi(x2, 0u, h);
        h = g2 | h;
        h = bfi(x3, 0u, h);
        unsigned G = g3 | h;   // (cnt_b > best) per column
        w0 = bfi(G, t0, w0); w1 = bfi(G, t1, w1);
        w2 = bfi(G, t2, w2); w3 = bfi(G, t3, w3);
        i0 = (b & 1) ? (i0 | G) : bfi(G, 0u, i0);
        i1 = (b & 2) ? (i1 | G) : bfi(G, 0u, i1);
        i2 = (b & 4) ? (i2 | G) : bfi(G, 0u, i2);
      }
    }
    p0 = i0; p1 = i1; p2 = i2;
  }

  // ---- final store: valid region = tile rows [8,56) x cols [8,56)
  if (r >= 8 && r < 56) {
    const int gy = by * OUT + r - 8;
    float* orow = out + (size_t)bz * IMG * IMG + (size_t)gy * IMG
                + bx * OUT + (w ? 24 : 0);
    const int jb = w ? 0 : 8;
#pragma unroll
    for (int g = 0; g < 6; ++g) {
      const int j = jb + 4 * g;
      float4 vv;
      vv.x = (float)(((p0 >> (j + 0)) & 1u) | (((p1 >> (j + 0)) & 1u) << 1) | (((p2 >> (j + 0)) & 1u) << 2));
      vv.y = (float)(((p0 >> (j + 1)) & 1u) | (((p1 >> (j + 1)) & 1u) << 1) | (((p2 >> (j + 1)) & 1u) << 2));
      vv.z = (float)(((p0 >> (j + 2)) & 1u) | (((p1 >> (j + 2)) & 1u) << 1) | (((p2 >> (j + 2)) & 1u) << 2));
      vv.w = (float)(((p0 >> (j + 3)) & 1u) | (((p1 >> (j + 3)) & 1u) << 1) | (((p2 >> (j + 3)) & 1u) << 2));
      *(float4*)(orow + 4 * g) = vv;
    }
  }
}

extern "C" void kernel_launch(void* const* d_in, const int* in_sizes, int n_in,
                              void* d_out, int out_size, void* d_ws, size_t ws_size,
                              hipStream_t stream) {
  const float* clusters = (const float*)d_in[0];
  (void)in_sizes; (void)n_in; (void)out_size; (void)d_ws; (void)ws_size;

  dim3 grid(NB, NB, 8);   // 16 x 16 tiles x batch 8
  fused_bitslice<<<grid, 128, 0, stream>>>(clusters, (float*)d_out);
}

// Round 5
// 43.359 us; speedup vs baseline: 1.3509x; 1.0396x over previous
//
#include <hip/hip_runtime.h>

// 3x3 majority, replicate pad, 8 bins, ties -> smallest, 8 iterations, fused.
// Bit-sliced planes (3 bits/label), one u32 = 32 columns. Tile: 64x64 input
// (48x48 output), ONE wave per tile: lane = 2q+w owns rows {2q,2q+1} of word
// w. Horizontal 3-count H (2-bit/bin) via alignbit funnels + quad-perm DPP
// (lane^1 = other word). Vertical = H[r-1]+H[r]+H[r+1]; cross-pair H moved by
// ds_bpermute (lane+-2). Argmax = bitwise tournament (strict >, first-max).
// No LDS, no barriers. Halo: tile-edge garbage moves 1 px/iter <= 8 = halo.
// Image edges: column patch via bfi mask; row patch via cndmask at q==4/27.

static constexpr int IMG = 768;
static constexpr int OUT = 48;
static constexpr int NB  = 16;   // IMG / OUT

__device__ __forceinline__ unsigned bfi(unsigned m, unsigned a, unsigned b) {
  return (a & m) | (b & ~m);     // v_bfi_b32
}

struct C4 { unsigned b0, b1, b2, b3; };

__device__ __forceinline__ unsigned gt4(const C4& x, const C4& y) {  // x > y
  unsigned g = x.b0 & ~y.b0;
  unsigned a = x.b1 & ~y.b1, d = x.b1 ^ y.b1; g = (a & d) | (g & ~d);
  a = x.b2 & ~y.b2; d = x.b2 ^ y.b2; g = (a & d) | (g & ~d);
  a = x.b3 & ~y.b3; d = x.b3 ^ y.b3; g = (a & d) | (g & ~d);
  return g;
}
__device__ __forceinline__ C4 sel4(unsigned G, const C4& x, const C4& y) {
  C4 r; r.b0 = bfi(G, x.b0, y.b0); r.b1 = bfi(G, x.b1, y.b1);
  r.b2 = bfi(G, x.b2, y.b2); r.b3 = bfi(G, x.b3, y.b3); return r;
}

__device__ __forceinline__ void tourn8(const C4 c[8],
                                       unsigned& o0, unsigned& o1, unsigned& o2) {
  unsigned g01 = gt4(c[1], c[0]); C4 w01 = sel4(g01, c[1], c[0]);
  unsigned g23 = gt4(c[3], c[2]); C4 w23 = sel4(g23, c[3], c[2]);
  unsigned gA  = gt4(w23, w01);   C4 wA  = sel4(gA, w23, w01);
  unsigned iA0 = bfi(gA, g23, g01), iA1 = gA;
  unsigned g45 = gt4(c[5], c[4]); C4 w45 = sel4(g45, c[5], c[4]);
  unsigned g67 = gt4(c[7], c[6]); C4 w67 = sel4(g67, c[7], c[6]);
  unsigned gB  = gt4(w67, w45);   C4 wB  = sel4(gB, w67, w45);
  unsigned iB0 = bfi(gB, g67, g45), iB1 = gB;
  unsigned gR  = gt4(wB, wA);
  o0 = bfi(gR, iB0, iA0); o1 = bfi(gR, iB1, iA1); o2 = gR;
}

__device__ __forceinline__ void load_planes(const float* __restrict__ rp, int gx0,
                                            unsigned& P0, unsigned& P1, unsigned& P2) {
  float f[32];
  if (gx0 >= 0 && gx0 + 32 <= IMG) {
#pragma unroll
    for (int g = 0; g < 8; ++g)
      *reinterpret_cast<float4*>(f + 4 * g) =
          *reinterpret_cast<const float4*>(rp + gx0 + 4 * g);
  } else {
#pragma unroll
    for (int j = 0; j < 32; ++j) {
      int gx = gx0 + j; gx = gx < 0 ? 0 : (gx > IMG - 1 ? IMG - 1 : gx);
      f[j] = rp[gx];
    }
  }
  unsigned a0 = 0, a1 = 0, a2 = 0;
#pragma unroll
  for (int j = 0; j < 32; ++j) {
    unsigned u = (unsigned)(int)f[j];
    a0 |= (u & 1u) << j;
    a1 |= ((u >> 1) & 1u) << j;
    a2 |= ((u >> 2) & 1u) << j;
  }
  P0 = a0; P1 = a1; P2 = a2;
}

__global__ __launch_bounds__(64) void fused_shfl(
    const float* __restrict__ in, float* __restrict__ out) {
  const int bx = blockIdx.x, by = blockIdx.y, bz = blockIdx.z;
  const int lane = threadIdx.x;
  const int w = lane & 1;          // word (32-col half)
  const int q = lane >> 1;         // row pair: rows 2q, 2q+1

  const float* img = in + (size_t)bz * IMG * IMG;

  const bool edgeX = (bx == 0) || (bx == NB - 1);
  const unsigned maskL = (bx == 0 && w == 0) ? 0x100u : 0u;        // tile col 8
  const unsigned maskR = (bx == NB - 1 && w == 1) ? 0x00800000u : 0u; // col 55
  const bool q4 = (q == 4), q27 = (q == 27);
  const int upA = ((lane - 2) & 63) << 2;
  const int dnA = ((lane + 2) & 63) << 2;

  // ---- stage: rows 2q, 2q+1 (clamped), word w -> planes
  unsigned pa0, pa1, pa2, pb0, pb1, pb2;
  {
    const int gx0 = bx * OUT + w * 32 - 8;
    int gy = by * OUT - 8 + 2 * q;
    int gya = gy < 0 ? 0 : (gy > IMG - 1 ? IMG - 1 : gy);
    int gyb = gy + 1 < 0 ? 0 : (gy + 1 > IMG - 1 ? IMG - 1 : gy + 1);
    load_planes(img + (size_t)gya * IMG, gx0, pa0, pa1, pa2);
    load_planes(img + (size_t)gyb * IMG, gx0, pb0, pb1, pb2);
  }

#pragma unroll 1
  for (int it = 0; it < 8; ++it) {
    // ---- equality masks from planes
    unsigned ea[8], eb[8];
    {
      unsigned n0 = ~pa0, n1 = ~pa1, n2 = ~pa2;
      unsigned a00 = n1 & n0, a01 = n1 & pa0, a10 = pa1 & n0, a11 = pa1 & pa0;
      ea[0] = n2 & a00; ea[1] = n2 & a01; ea[2] = n2 & a10; ea[3] = n2 & a11;
      ea[4] = pa2 & a00; ea[5] = pa2 & a01; ea[6] = pa2 & a10; ea[7] = pa2 & a11;
    }
    {
      unsigned n0 = ~pb0, n1 = ~pb1, n2 = ~pb2;
      unsigned a00 = n1 & n0, a01 = n1 & pb0, a10 = pb1 & n0, a11 = pb1 & pb0;
      eb[0] = n2 & a00; eb[1] = n2 & a01; eb[2] = n2 & a10; eb[3] = n2 & a11;
      eb[4] = pb2 & a00; eb[5] = pb2 & a01; eb[6] = pb2 & a10; eb[7] = pb2 & a11;
    }

    // ---- horizontal 2-bit counts H per bin per row
    unsigned HaL[8], HaH[8], HbL[8], HbH[8];
#pragma unroll
    for (int b_ = 0; b_ < 8; ++b_) {
      unsigned e = ea[b_];
      unsigned n = (unsigned)__builtin_amdgcn_update_dpp(
          0, (int)e, 0xB1, 0xF, 0xF, true);                // lane^1 (quad_perm)
      unsigned A = __builtin_amdgcn_alignbit(e, n, 31);    // left neighbor col
      unsigned C = __builtin_amdgcn_alignbit(n, e, 1);     // right neighbor col
      if (edgeX) { A = bfi(maskL, e, A); C = bfi(maskR, e, C); }
      unsigned t = A ^ e;
      HaL[b_] = t ^ C; HaH[b_] = bfi(t, C, e);             // sum, majority
      e = eb[b_];
      n = (unsigned)__builtin_amdgcn_update_dpp(0, (int)e, 0xB1, 0xF, 0xF, true);
      A = __builtin_amdgcn_alignbit(e, n, 31);
      C = __builtin_amdgcn_alignbit(n, e, 1);
      if (edgeX) { A = bfi(maskL, e, A); C = bfi(maskR, e, C); }
      t = A ^ e;
      HbL[b_] = t ^ C; HbH[b_] = bfi(t, C, e);
    }

    // ---- row a: Hm = H[2q-1] from lane-2 (its row b)
    unsigned na0, na1, na2;
    {
      unsigned HmL[8], HmH[8];
#pragma unroll
      for (int b_ = 0; b_ < 8; ++b_) {
        HmL[b_] = (unsigned)__builtin_amdgcn_ds_bpermute(upA, (int)HbL[b_]);
        HmH[b_] = (unsigned)__builtin_amdgcn_ds_bpermute(upA, (int)HbH[b_]);
      }
      if (by == 0) {
#pragma unroll
        for (int b_ = 0; b_ < 8; ++b_) {
          HmL[b_] = q4 ? HaL[b_] : HmL[b_];   // image row 0: up -> self
          HmH[b_] = q4 ? HaH[b_] : HmH[b_];
        }
      }
      C4 ca[8];
#pragma unroll
      for (int b_ = 0; b_ < 8; ++b_) {
        unsigned s0 = HaL[b_] ^ HbL[b_], cc = HaL[b_] & HbL[b_];
        unsigned xx = HaH[b_] ^ HbH[b_];
        unsigned s1 = xx ^ cc, s2 = bfi(xx, cc, HbH[b_]);   // S = Ha + Hb
        unsigned t0 = s0 ^ HmL[b_], k0 = s0 & HmL[b_], yy = s1 ^ HmH[b_];
        ca[b_].b0 = t0; ca[b_].b1 = yy ^ k0;
        unsigned k1 = bfi(yy, k0, HmH[b_]);
        ca[b_].b2 = s2 ^ k1; ca[b_].b3 = s2 & k1;           // count = S + Hm
      }
      tourn8(ca, na0, na1, na2);
    }

    // ---- row b: Hq = H[2q+2] from lane+2 (its row a)
    {
      unsigned HqL[8], HqH[8];
#pragma unroll
      for (int b_ = 0; b_ < 8; ++b_) {
        HqL[b_] = (unsigned)__builtin_amdgcn_ds_bpermute(dnA, (int)HaL[b_]);
        HqH[b_] = (unsigned)__builtin_amdgcn_ds_bpermute(dnA, (int)HaH[b_]);
      }
      if (by == NB - 1) {
#pragma unroll
        for (int b_ = 0; b_ < 8; ++b_) {
          HqL[b_] = q27 ? HbL[b_] : HqL[b_];  // image row 767: down -> self
          HqH[b_] = q27 ? HbH[b_] : HqH[b_];
        }
      }
      C4 cb[8];
#pragma unroll
      for (int b_ = 0; b_ < 8; ++b_) {
        unsigned s0 = HaL[b_] ^ HbL[b_], cc = HaL[b_] & HbL[b_];
        unsigned xx = HaH[b_] ^ HbH[b_];
        unsigned s1 = xx ^ cc, s2 = bfi(xx, cc, HbH[b_]);
        unsigned t0 = s0 ^ HqL[b_], k0 = s0 & HqL[b_], yy = s1 ^ HqH[b_];
        cb[b_].b0 = t0; cb[b_].b1 = yy ^ k0;
        unsigned k1 = bfi(yy, k0, HqH[b_]);
        cb[b_].b2 = s2 ^ k1; cb[b_].b3 = s2 & k1;
      }
      tourn8(cb, pb0, pb1, pb2);
    }
    pa0 = na0; pa1 = na1; pa2 = na2;
  }

  // ---- store: valid rows 8..55 (q in [4,27]), valid cols 8..55
  if (q >= 4 && q <= 27) {
    float* oimg = out + (size_t)bz * IMG * IMG;
    const int gxb = bx * OUT + (w ? 24 : 0);
    const int jb = w ? 0 : 8;
#pragma unroll
    for (int rr = 0; rr < 2; ++rr) {
      unsigned P0 = rr ? pb0 : pa0;
      unsigned P1 = rr ? pb1 : pa1;
      unsigned P2 = rr ? pb2 : pa2;
      const int gy = by * OUT + 2 * q + rr - 8;
      float* orow = oimg + (size_t)gy * IMG + gxb;
#pragma unroll
      for (int g_ = 0; g_ < 6; ++g_) {
        const int j = jb + 4 * g_;
        float4 v;
        v.x = (float)(((P0 >> (j + 0)) & 1u) | (((P1 >> (j + 0)) & 1u) << 1) | (((P2 >> (j + 0)) & 1u) << 2));
        v.y = (float)(((P0 >> (j + 1)) & 1u) | (((P1 >> (j + 1)) & 1u) << 1) | (((P2 >> (j + 1)) & 1u) << 2));
        v.z = (float)(((P0 >> (j + 2)) & 1u) | (((P1 >> (j + 2)) & 1u) << 1) | (((P2 >> (j + 2)) & 1u) << 2));
        v.w = (float)(((P0 >> (j + 3)) & 1u) | (((P1 >> (j + 3)) & 1u) << 1) | (((P2 >> (j + 3)) & 1u) << 2));
        *reinterpret_cast<float4*>(orow + 4 * g_) = v;
      }
    }
  }
}

extern "C" void kernel_launch(void* const* d_in, const int* in_sizes, int n_in,
                              void* d_out, int out_size, void* d_ws, size_t ws_size,
                              hipStream_t stream) {
  const float* clusters = (const float*)d_in[0];
  (void)in_sizes; (void)n_in; (void)out_size; (void)d_ws; (void)ws_size;

  dim3 grid(NB, NB, 8);   // 16 x 16 tiles x batch 8, one wave per tile
  fused_shfl<<<grid, 64, 0, stream>>>(clusters, (float*)d_out);
}